// Round 1
// baseline (1308.527 us; speedup 1.0000x reference)
//
#include <hip/hip_runtime.h>

#define IN_DIM 256
#define OUT_DIM 64

// --- count incoming edges per node (targets = col) ---
__global__ void deg_kernel(const int* __restrict__ col, int* __restrict__ deg, int E) {
    int e = blockIdx.x * blockDim.x + threadIdx.x;
    if (e < E) atomicAdd(&deg[col[e]], 1);
}

// --- single-block exclusive scan over deg -> start/cursor; also dinv = rsqrt(deg+1) ---
__global__ void scan_kernel(const int* __restrict__ deg, int* __restrict__ start,
                            int* __restrict__ cursor, float* __restrict__ dinv, int N) {
    __shared__ int lsum[1024];
    int t = threadIdx.x;
    int CH = (N + 1023) >> 10;           // elements per thread
    int lo = t * CH;
    int hi = lo + CH; if (hi > N) hi = N;
    int s = 0;
    for (int i = lo; i < hi; i++) s += deg[i];
    lsum[t] = s;
    __syncthreads();
    // Hillis-Steele inclusive scan (read-barrier-write is hazard-free)
    for (int off = 1; off < 1024; off <<= 1) {
        int v = (t >= off) ? lsum[t - off] : 0;
        __syncthreads();
        lsum[t] += v;
        __syncthreads();
    }
    int run = (t == 0) ? 0 : lsum[t - 1];
    for (int i = lo; i < hi; i++) {
        start[i] = run;
        cursor[i] = run;
        int d = deg[i];
        dinv[i] = rsqrtf((float)(d + 1));   // +1 = self loop
        run += d;
    }
    if (t == 1023) start[N] = run;          // == E
}

// --- h = x @ W, fp32. One wave handles 8 rows x 64 cols; W staged in LDS. ---
__global__ void __launch_bounds__(256) gemm_kernel(const float* __restrict__ x,
                                                   const float* __restrict__ W,
                                                   float* __restrict__ h, int N) {
    __shared__ float Wl[IN_DIM * OUT_DIM];          // 64 KB
    int t = threadIdx.x;
    const float4* W4 = (const float4*)W;
    float4* Wl4 = (float4*)Wl;
#pragma unroll
    for (int i = 0; i < 16; i++) Wl4[t + i * 256] = W4[t + i * 256];
    __syncthreads();

    int wave = t >> 6, lane = t & 63;
    int r0 = (blockIdx.x * 4 + wave) * 8;
    if (r0 >= N) return;

    float acc[8];
#pragma unroll
    for (int rr = 0; rr < 8; rr++) acc[rr] = 0.f;

    const float4* x4 = (const float4*)x + (size_t)r0 * (IN_DIM / 4);
#pragma unroll 4
    for (int k4 = 0; k4 < IN_DIM / 4; k4++) {
        float w0 = Wl[(4 * k4 + 0) * OUT_DIM + lane];
        float w1 = Wl[(4 * k4 + 1) * OUT_DIM + lane];
        float w2 = Wl[(4 * k4 + 2) * OUT_DIM + lane];
        float w3 = Wl[(4 * k4 + 3) * OUT_DIM + lane];
#pragma unroll
        for (int rr = 0; rr < 8; rr++) {
            float4 xv = x4[rr * (IN_DIM / 4) + k4];
            acc[rr] = fmaf(xv.x, w0, acc[rr]);
            acc[rr] = fmaf(xv.y, w1, acc[rr]);
            acc[rr] = fmaf(xv.z, w2, acc[rr]);
            acc[rr] = fmaf(xv.w, w3, acc[rr]);
        }
    }
#pragma unroll
    for (int rr = 0; rr < 8; rr++)
        h[(size_t)(r0 + rr) * OUT_DIM + lane] = acc[rr];
}

// --- scatter edges into CSC: csr[start[c]..start[c+1]) = source rows of c ---
__global__ void fill_kernel(const int* __restrict__ row, const int* __restrict__ col,
                            int* __restrict__ cursor, int* __restrict__ csr, int E) {
    int e = blockIdx.x * blockDim.x + threadIdx.x;
    if (e < E) {
        int c = col[e];
        int pos = atomicAdd(&cursor[c], 1);
        csr[pos] = row[e];
    }
}

// --- pull aggregation + bias + min-max scale + L2 normalize, one wave per node ---
__global__ void __launch_bounds__(256) agg_kernel(const float* __restrict__ h,
                                                  const int* __restrict__ start,
                                                  const int* __restrict__ csr,
                                                  const float* __restrict__ dinv,
                                                  const float* __restrict__ b,
                                                  float* __restrict__ out, int N) {
    int t = threadIdx.x;
    int wave = t >> 6, lane = t & 63;
    int c = blockIdx.x * 4 + wave;
    if (c >= N) return;

    float dc = dinv[c];
    // self-loop term: dc*dc*h[c]  (outer dc applied below)
    float acc = h[(size_t)c * OUT_DIM + lane] * dc;
    int s = start[c], e2 = start[c + 1];
    for (int p = s; p < e2; p++) {
        int r = csr[p];
        acc = fmaf(dinv[r], h[(size_t)r * OUT_DIM + lane], acc);
    }
    acc = fmaf(acc, dc, b[lane]);

    // row min / max across the 64 lanes
    float mn = acc, mx = acc;
#pragma unroll
    for (int m = 32; m > 0; m >>= 1) {
        mn = fminf(mn, __shfl_xor(mn, m));
        mx = fmaxf(mx, __shfl_xor(mx, m));
    }
    float z = (acc - mn) / (mx - mn);
    float sq = z * z;
#pragma unroll
    for (int m = 32; m > 0; m >>= 1) sq += __shfl_xor(sq, m);
    out[(size_t)c * OUT_DIM + lane] = z / fmaxf(sqrtf(sq), 1e-12f);
}

extern "C" void kernel_launch(void* const* d_in, const int* in_sizes, int n_in,
                              void* d_out, int out_size, void* d_ws, size_t ws_size,
                              hipStream_t stream) {
    const float* x = (const float*)d_in[0];
    const int*   ei = (const int*)d_in[1];
    const float* W = (const float*)d_in[2];
    const float* b = (const float*)d_in[3];
    float* out = (float*)d_out;

    int N = in_sizes[0] / IN_DIM;      // 100000
    int E = in_sizes[1] / 2;           // 3200000
    const int* row = ei;               // edge_index[0]
    const int* col = ei + E;           // edge_index[1]

    // workspace layout (~40 MB)
    char* w = (char*)d_ws;
    float* h     = (float*)w; w += (size_t)N * OUT_DIM * 4;
    int*   deg   = (int*)w;   w += (size_t)N * 4;
    int*   start = (int*)w;   w += (size_t)(N + 1) * 4;
    int*   curs  = (int*)w;   w += (size_t)N * 4;
    float* dinv  = (float*)w; w += (size_t)N * 4;
    int*   csr   = (int*)w;   w += (size_t)E * 4;

    hipMemsetAsync(deg, 0, (size_t)N * 4, stream);

    int eb = (E + 255) / 256;
    deg_kernel<<<eb, 256, 0, stream>>>(col, deg, E);
    scan_kernel<<<1, 1024, 0, stream>>>(deg, start, curs, dinv, N);
    gemm_kernel<<<(N + 31) / 32, 256, 0, stream>>>(x, W, h, N);
    fill_kernel<<<eb, 256, 0, stream>>>(row, col, curs, csr, E);
    agg_kernel<<<(N + 3) / 4, 256, 0, stream>>>(h, start, csr, dinv, b, out, N);
}

// Round 2
// 1176.283 us; speedup vs baseline: 1.1124x; 1.1124x over previous
//
#include <hip/hip_runtime.h>

#define IN_DIM 256
#define OUT_DIM 64

// --- in-degree histogram over targets (self-loop added in dinv) ---
__global__ void deg_kernel(const int* __restrict__ col, int* __restrict__ deg, int E) {
    int e = blockIdx.x * blockDim.x + threadIdx.x;
    if (e < E) atomicAdd(&deg[col[e]], 1);
}

__global__ void dinv_kernel(const int* __restrict__ deg, float* __restrict__ dinv, int N) {
    int i = blockIdx.x * blockDim.x + threadIdx.x;
    if (i < N) dinv[i] = rsqrtf((float)(deg[i] + 1));
}

// --- hs = dinv[row] * (x @ W), fp32. Wave = 8 rows x 64 cols; W staged in LDS. ---
__global__ void __launch_bounds__(256) gemm_kernel(const float* __restrict__ x,
                                                   const float* __restrict__ W,
                                                   const float* __restrict__ dinv,
                                                   float* __restrict__ hs, int N) {
    __shared__ float Wl[IN_DIM * OUT_DIM];          // 64 KB
    int t = threadIdx.x;
    const float4* W4 = (const float4*)W;
    float4* Wl4 = (float4*)Wl;
#pragma unroll
    for (int i = 0; i < 16; i++) Wl4[t + i * 256] = W4[t + i * 256];
    __syncthreads();

    int wave = t >> 6, lane = t & 63;
    int r0 = (blockIdx.x * 4 + wave) * 8;
    if (r0 >= N) return;

    float acc[8];
#pragma unroll
    for (int rr = 0; rr < 8; rr++) acc[rr] = 0.f;

    const float4* x4 = (const float4*)x + (size_t)r0 * (IN_DIM / 4);
#pragma unroll 4
    for (int k4 = 0; k4 < IN_DIM / 4; k4++) {
        float w0 = Wl[(4 * k4 + 0) * OUT_DIM + lane];
        float w1 = Wl[(4 * k4 + 1) * OUT_DIM + lane];
        float w2 = Wl[(4 * k4 + 2) * OUT_DIM + lane];
        float w3 = Wl[(4 * k4 + 3) * OUT_DIM + lane];
#pragma unroll
        for (int rr = 0; rr < 8; rr++) {
            float4 xv = x4[rr * (IN_DIM / 4) + k4];
            acc[rr] = fmaf(xv.x, w0, acc[rr]);
            acc[rr] = fmaf(xv.y, w1, acc[rr]);
            acc[rr] = fmaf(xv.z, w2, acc[rr]);
            acc[rr] = fmaf(xv.w, w3, acc[rr]);
        }
    }
#pragma unroll
    for (int rr = 0; rr < 8; rr++)
        hs[(size_t)(r0 + rr) * OUT_DIM + lane] = acc[rr] * dinv[r0 + rr];
}

// --- push: per edge, wave-wide atomicAdd of hs[row] into out[col] ---
__global__ void __launch_bounds__(256) push_kernel(const int* __restrict__ row,
                                                   const int* __restrict__ col,
                                                   const float* __restrict__ hs,
                                                   float* __restrict__ out,
                                                   int E, int epw) {
    int wid = blockIdx.x * 4 + (threadIdx.x >> 6);
    int lane = threadIdx.x & 63;
    int e0 = wid * epw;
    int e1 = e0 + epw; if (e1 > E) e1 = E;
    int e = e0;
    for (; e + 4 <= e1; e += 4) {
        int r0 = row[e + 0], c0 = col[e + 0];
        int r1 = row[e + 1], c1 = col[e + 1];
        int r2 = row[e + 2], c2 = col[e + 2];
        int r3 = row[e + 3], c3 = col[e + 3];
        float v0 = hs[(size_t)r0 * OUT_DIM + lane];
        float v1 = hs[(size_t)r1 * OUT_DIM + lane];
        float v2 = hs[(size_t)r2 * OUT_DIM + lane];
        float v3 = hs[(size_t)r3 * OUT_DIM + lane];
        atomicAdd(out + (size_t)c0 * OUT_DIM + lane, v0);
        atomicAdd(out + (size_t)c1 * OUT_DIM + lane, v1);
        atomicAdd(out + (size_t)c2 * OUT_DIM + lane, v2);
        atomicAdd(out + (size_t)c3 * OUT_DIM + lane, v3);
    }
    for (; e < e1; ++e) {
        int r = row[e], c = col[e];
        atomicAdd(out + (size_t)c * OUT_DIM + lane, hs[(size_t)r * OUT_DIM + lane]);
    }
}

// --- epilogue: total = dc*(agg + hs[c]) + b; row min-max scale; row L2 normalize ---
__global__ void __launch_bounds__(256) epi_kernel(const float* __restrict__ hs,
                                                  const float* __restrict__ dinv,
                                                  const float* __restrict__ b,
                                                  float* __restrict__ out, int N) {
    int t = threadIdx.x;
    int c = blockIdx.x * 4 + (t >> 6);
    int lane = t & 63;
    if (c >= N) return;

    float dc = dinv[c];
    float tot = fmaf(dc, out[(size_t)c * OUT_DIM + lane] + hs[(size_t)c * OUT_DIM + lane],
                     b[lane]);

    float mn = tot, mx = tot;
#pragma unroll
    for (int m = 32; m > 0; m >>= 1) {
        mn = fminf(mn, __shfl_xor(mn, m));
        mx = fmaxf(mx, __shfl_xor(mx, m));
    }
    float z = (tot - mn) / (mx - mn);
    float sq = z * z;
#pragma unroll
    for (int m = 32; m > 0; m >>= 1) sq += __shfl_xor(sq, m);
    out[(size_t)c * OUT_DIM + lane] = z / fmaxf(sqrtf(sq), 1e-12f);
}

extern "C" void kernel_launch(void* const* d_in, const int* in_sizes, int n_in,
                              void* d_out, int out_size, void* d_ws, size_t ws_size,
                              hipStream_t stream) {
    const float* x = (const float*)d_in[0];
    const int*   ei = (const int*)d_in[1];
    const float* W = (const float*)d_in[2];
    const float* b = (const float*)d_in[3];
    float* out = (float*)d_out;

    int N = in_sizes[0] / IN_DIM;      // 100000
    int E = in_sizes[1] / 2;           // 3200000
    const int* row = ei;               // edge_index[0] (source)
    const int* col = ei + E;           // edge_index[1] (target)

    // workspace: hs [N,64] f32, deg [N] i32, dinv [N] f32  (~26.4 MB)
    char* w = (char*)d_ws;
    float* hs   = (float*)w; w += (size_t)N * OUT_DIM * 4;
    int*   deg  = (int*)w;   w += (size_t)N * 4;
    float* dinv = (float*)w; w += (size_t)N * 4;

    hipMemsetAsync(deg, 0, (size_t)N * 4, stream);
    hipMemsetAsync(out, 0, (size_t)out_size * 4, stream);

    int eb = (E + 255) / 256;
    deg_kernel<<<eb, 256, 0, stream>>>(col, deg, E);
    dinv_kernel<<<(N + 255) / 256, 256, 0, stream>>>(deg, dinv, N);
    gemm_kernel<<<(N + 31) / 32, 256, 0, stream>>>(x, W, dinv, hs, N);

    int pblocks = 2048;                       // 8192 waves
    int epw = (E + pblocks * 4 - 1) / (pblocks * 4);
    push_kernel<<<pblocks, 256, 0, stream>>>(row, col, hs, out, E, epw);

    epi_kernel<<<(N + 3) / 4, 256, 0, stream>>>(hs, dinv, b, out, N);
}